// Round 5
// baseline (128.199 us; speedup 1.0000x reference)
//
#include <hip/hip_runtime.h>

// out[b,o,n] = sum_h W[n,o,h] * x[b,h,n] + bias[n,o]
// x: [16][32][50000] f32, W: [50000][32][32] f32, bias: [50000][32] f32
// Per node: D[o 32][b 16] = W_n[32o x 32h] . X_n[32h x 16b] via 2x mfma 16x16x32 bf16.

#define NN 50000
#define CH 32
#define NT 32          // nodes per block
#define TPB 256        // 4 waves, 8 nodes per wave
#define NXCD 8

typedef __attribute__((ext_vector_type(8))) short bf16x8;
typedef __attribute__((ext_vector_type(4))) float f32x4;
typedef __attribute__((ext_vector_type(4))) unsigned short bf16x4;

__device__ inline unsigned short f2bf(float f) {
    union { float f; unsigned u; } v; v.f = f;
    return (unsigned short)((v.u + 0x7fffu + ((v.u >> 16) & 1u)) >> 16);
}

__global__ __launch_bounds__(TPB, 5)
void localconv1d_kernel(const float* __restrict__ x,
                        const float* __restrict__ W,
                        const float* __restrict__ bias,
                        float* __restrict__ out) {
    // x tile as bf16 B-fragments: element (b,h,nn) at byte
    //   nn*1024 + (h>>3)*256 + b*16 + (h&7)*2, XOR'd with ((nn>>2)&7)<<4.
    // Read side: lane l of node nn reads 16B at nn*1024 + l*16 (same XOR) ->
    //   lane-contiguous 1KB ds_read_b128 (bank floor, no conflicts).
    __shared__ unsigned short xs[NT * 512];   // 32 KB

    const int tid = threadIdx.x;

    // ---- bijective XCD-aware block swizzle (nwg = 1563 = 8*195 + 3) ----
    const int nwg  = (NN + NT - 1) / NT;
    const int q    = nwg / NXCD;
    const int r    = nwg % NXCD;
    const int orig = blockIdx.x;
    const int xcd  = orig % NXCD;
    const int wgid = (xcd < r ? xcd * (q + 1) : r * (q + 1) + (xcd - r) * q)
                     + orig / NXCD;
    int n0 = wgid * NT;
    if (n0 > NN - NT) n0 = NN - NT;   // tail: overlap-recompute (benign dup writes)

    // ---- stage x -> LDS bf16 fragments ----
    // unit u: thread covers 4-row group gi = (tid>>3) + u*32, chunk = tid&7
    // rows = gi*4 + k, k=0..3 (b = gi>>3, h = (gi&7)*4 + k); 128B contiguous per row
    {
        const int chunk = tid & 7;            // nodes chunk*4 .. chunk*4+3
        float4 xv[4][4];
        #pragma unroll
        for (int u = 0; u < 4; ++u) {
            int gi = (tid >> 3) + u * 32;
            #pragma unroll
            for (int k = 0; k < 4; ++k) {
                int row = gi * 4 + k;         // b*32 + h
                xv[u][k] = *reinterpret_cast<const float4*>(
                    x + (size_t)row * NN + n0 + chunk * 4);
            }
        }
        #pragma unroll
        for (int u = 0; u < 4; ++u) {
            int gi = (tid >> 3) + u * 32;
            int b  = gi >> 3;
            int h4 = gi & 7;                  // h = h4*4 + k
            int hg = h4 >> 1;                 // h>>3
            int jb = (h4 & 1) * 8;            // byte offset of j0 in the 16B slot
            #pragma unroll
            for (int c = 0; c < 4; ++c) {     // node within chunk
                int nn = chunk * 4 + c;
                unsigned base = (unsigned)(nn * 1024 + hg * 256 + b * 16 + jb);
                base ^= ((unsigned)(nn >> 2) & 7u) << 4;
                bf16x4 pk;
                pk[0] = f2bf(((const float*)&xv[u][0])[c]);
                pk[1] = f2bf(((const float*)&xv[u][1])[c]);
                pk[2] = f2bf(((const float*)&xv[u][2])[c]);
                pk[3] = f2bf(((const float*)&xv[u][3])[c]);
                *reinterpret_cast<bf16x4*>((char*)xs + base) = pk;
            }
        }
    }
    __syncthreads();

    const int lane = tid & 63;
    const int wv   = tid >> 6;     // wave 0..3, owns nodes wv*8 .. wv*8+7
    const int bl   = lane & 15;
    const int hc   = lane >> 4;    // k-group (8 h each)

    #pragma unroll
    for (int grp = 0; grp < 2; ++grp) {
        f32x4 acc[4][2];
        #pragma unroll
        for (int g = 0; g < 4; ++g) {
            int nn = wv * 8 + grp * 4 + g;
            int n  = n0 + nn;

            // B fragment (x) from LDS: lane-contiguous 16B
            unsigned raddr = (unsigned)(nn * 1024 + lane * 16);
            raddr ^= ((unsigned)(nn >> 2) & 7u) << 4;
            bf16x8 bfrag = *reinterpret_cast<const bf16x8*>((const char*)xs + raddr);

            #pragma unroll
            for (int H = 0; H < 2; ++H) {
                // A fragment (W): lane holds W[n, o=16H+bl, h=hc*8+j]
                const float* wp = W + (((size_t)n * CH) + 16 * H + bl) * CH + hc * 8;
                float4 w0 = *reinterpret_cast<const float4*>(wp);
                float4 w1 = *reinterpret_cast<const float4*>(wp + 4);
                bf16x8 afrag;
                afrag[0] = f2bf(w0.x); afrag[1] = f2bf(w0.y);
                afrag[2] = f2bf(w0.z); afrag[3] = f2bf(w0.w);
                afrag[4] = f2bf(w1.x); afrag[5] = f2bf(w1.y);
                afrag[6] = f2bf(w1.z); afrag[7] = f2bf(w1.w);

                // C init with bias: lane r-th acc = bias[n, 16H + 4*hc + r]
                f32x4 c = *reinterpret_cast<const f32x4*>(
                    bias + (size_t)n * CH + 16 * H + 4 * hc);

                acc[g][H] = __builtin_amdgcn_mfma_f32_16x16x32_bf16(afrag, bfrag, c, 0, 0, 0);
            }
        }

        // stores: lane holds D[o = 16H + 4*hc + r][b = bl]; float4 along n over g
        #pragma unroll
        for (int H = 0; H < 2; ++H) {
            #pragma unroll
            for (int rr = 0; rr < 4; ++rr) {
                float4 vout;
                vout.x = acc[0][H][rr];
                vout.y = acc[1][H][rr];
                vout.z = acc[2][H][rr];
                vout.w = acc[3][H][rr];
                int o = 16 * H + 4 * hc + rr;
                *reinterpret_cast<float4*>(
                    out + ((size_t)bl * CH + o) * NN + n0 + wv * 8 + grp * 4) = vout;
            }
        }
    }
}

extern "C" void kernel_launch(void* const* d_in, const int* in_sizes, int n_in,
                              void* d_out, int out_size, void* d_ws, size_t ws_size,
                              hipStream_t stream) {
    const float* x    = (const float*)d_in[0];
    const float* W    = (const float*)d_in[1];
    const float* bias = (const float*)d_in[2];
    float* out        = (float*)d_out;

    const int blocks = (NN + NT - 1) / NT;   // 1563
    localconv1d_kernel<<<blocks, TPB, 0, stream>>>(x, W, bias, out);
}

// Round 6
// 97.767 us; speedup vs baseline: 1.3113x; 1.3113x over previous
//
#include <hip/hip_runtime.h>

// out[b,o,n] = sum_h W[n,o,h] * x[b,h,n] + bias[n,o]
// x: [16][32][50000] f32, W: [50000][32][32] f32, bias: [50000][32] f32
// Per node: D[o 32][b 16] = W_n[32o x 32h] . X_n[32h x 16b] via 2x mfma 16x16x32 bf16.
// W is streamed HBM -> LDS with global_load_lds (frag-order permuted source),
// per-wave double-buffered, counted vmcnt - no barriers in the main loop.

#define NN 50000
#define CH 32
#define NT 32          // nodes per block
#define TPB 256        // 4 waves; wave wv owns nodes wv*8 .. wv*8+7
#define NXCD 8

typedef __attribute__((ext_vector_type(8))) short bf16x8;
typedef __attribute__((ext_vector_type(4))) float f32x4;
typedef __attribute__((ext_vector_type(4))) unsigned short bf16x4;
typedef float __attribute__((address_space(1))) gf32;
typedef float __attribute__((address_space(3))) lf32;

__device__ inline unsigned short f2bf(float f) {
    union { float f; unsigned u; } v; v.f = f;
    return (unsigned short)((v.u + 0x7fffu + ((v.u >> 16) & 1u)) >> 16);
}

__global__ __launch_bounds__(TPB, 3)
void localconv1d_kernel(const float* __restrict__ x,
                        const float* __restrict__ W,
                        const float* __restrict__ bias,
                        float* __restrict__ out) {
    // LDS carve: [0,32768) x-tile bf16 frags (reused as f32 scratch in epilogue)
    //            [32768,49152) W double-buffers: wave wv at +wv*4096, buf at +buf*2048
    //            [49152,53248) bias tile (1024 f32)
    __shared__ char smem[53248];
    unsigned short* xs   = (unsigned short*)smem;
    char*           wlds = smem + 32768;
    float*          blds = (float*)(smem + 49152);
    float*          scr  = (float*)smem;

    const int tid  = threadIdx.x;
    const int lane = tid & 63;
    const int wv   = tid >> 6;

    // ---- bijective XCD-aware block swizzle (nwg = 1563 = 8*195 + 3) ----
    const int nwg  = (NN + NT - 1) / NT;
    const int q    = nwg / NXCD;
    const int r    = nwg % NXCD;
    const int orig = blockIdx.x;
    const int xcd  = orig % NXCD;
    const int wgid = (xcd < r ? xcd * (q + 1) : r * (q + 1) + (xcd - r) * q)
                     + orig / NXCD;
    int n0 = wgid * NT;
    if (n0 > NN - NT) n0 = NN - NT;   // tail: overlap-recompute (identical dup writes)

    // ---- bias -> LDS (drains at the staging barrier; not in counted stream) ----
    __builtin_amdgcn_global_load_lds(
        (const gf32*)(bias + (size_t)n0 * CH + wv * 256 + lane * 4),
        (lf32*)(blds + wv * 256), 16, 0, 0);

    // ---- stage x -> LDS bf16 B-fragments (R5-validated layout, 0 conflicts) ----
    {
        const int chunk = tid & 7;
        float4 xv[4][4];
        #pragma unroll
        for (int u = 0; u < 4; ++u) {
            int gi = (tid >> 3) + u * 32;
            #pragma unroll
            for (int k = 0; k < 4; ++k) {
                int row = gi * 4 + k;                 // b*32 + h
                xv[u][k] = *reinterpret_cast<const float4*>(
                    x + (size_t)row * NN + n0 + chunk * 4);
            }
        }
        #pragma unroll
        for (int u = 0; u < 4; ++u) {
            int gi = (tid >> 3) + u * 32;
            int b  = gi >> 3;
            int h4 = gi & 7;
            int hg = h4 >> 1;
            int jb = (h4 & 1) * 8;
            #pragma unroll
            for (int c = 0; c < 4; ++c) {
                int nn = chunk * 4 + c;
                unsigned base = (unsigned)(nn * 1024 + hg * 256 + b * 16 + jb);
                base ^= ((unsigned)(nn >> 2) & 7u) << 4;
                bf16x4 pk;
                pk[0] = f2bf(((const float*)&xv[u][0])[c]);
                pk[1] = f2bf(((const float*)&xv[u][1])[c]);
                pk[2] = f2bf(((const float*)&xv[u][2])[c]);
                pk[3] = f2bf(((const float*)&xv[u][3])[c]);
                *reinterpret_cast<bf16x4*>((char*)xs + base) = pk;
            }
        }
    }
    __syncthreads();   // x + bias ready; vmcnt drained to 0 here

    // ---- W pipeline: step s = node(g=s>>1) x o-half(H=s&1), 2KB per step ----
    // source pre-permuted into A-frag order: lane l fetches
    //   W[n, o=16H+(l&15), h=(l>>4)*8 + {0..3 | 4..7}] -> LDS linear lane*16.
    #define ISSUE_W(s_)                                                          \
        do {                                                                     \
            int g_ = (s_) >> 1, H_ = (s_) & 1;                                   \
            const float* src_ = W + (size_t)(n0 + wv * 8 + g_) * 1024            \
                                + (16 * H_ + (lane & 15)) * 32 + (lane >> 4) * 8;\
            char* dst_ = wlds + wv * 4096 + ((s_) & 1) * 2048;                   \
            __builtin_amdgcn_global_load_lds((const gf32*)src_,                  \
                                             (lf32*)dst_, 16, 0, 0);             \
            __builtin_amdgcn_global_load_lds((const gf32*)(src_ + 4),            \
                                             (lf32*)(dst_ + 1024), 16, 0, 0);    \
        } while (0)

    ISSUE_W(0);
    ISSUE_W(1);

    const int hc = lane >> 4;
    f32x4 acc[8][2];

    #pragma unroll
    for (int s = 0; s < 16; ++s) {
        if (s == 15) { asm volatile("s_waitcnt vmcnt(0)" ::: "memory"); }
        else         { asm volatile("s_waitcnt vmcnt(2)" ::: "memory"); }
        __builtin_amdgcn_sched_barrier(0);

        const int g  = s >> 1;
        const int Hh = s & 1;
        const int nn = wv * 8 + g;

        const char* wb = wlds + wv * 4096 + (s & 1) * 2048;
        f32x4 wlo = *reinterpret_cast<const f32x4*>(wb + lane * 16);
        f32x4 whi = *reinterpret_cast<const f32x4*>(wb + 1024 + lane * 16);

        f32x4 cfr = *reinterpret_cast<const f32x4*>(blds + nn * 32 + 16 * Hh + 4 * hc);

        unsigned raddr = (unsigned)(nn * 1024 + lane * 16);
        raddr ^= ((unsigned)(nn >> 2) & 7u) << 4;
        bf16x8 bfrag = *reinterpret_cast<const bf16x8*>((const char*)xs + raddr);

        bf16x8 afrag;
        afrag[0] = f2bf(wlo[0]); afrag[1] = f2bf(wlo[1]);
        afrag[2] = f2bf(wlo[2]); afrag[3] = f2bf(wlo[3]);
        afrag[4] = f2bf(whi[0]); afrag[5] = f2bf(whi[1]);
        afrag[6] = f2bf(whi[2]); afrag[7] = f2bf(whi[3]);

        // W buffer (s&1) is free once wlo/whi are in VGPRs (lgkmcnt drained by
        // the cvt uses above); pin refill below that point.
        __builtin_amdgcn_sched_barrier(0);
        if (s + 2 < 16) ISSUE_W(s + 2);

        acc[g][Hh] = __builtin_amdgcn_mfma_f32_16x16x32_bf16(afrag, bfrag, cfr, 0, 0, 0);
    }

    // ---- epilogue: LDS transpose so every store inst writes 8 full 128B lines ----
    // scratch: 128 rows x stride 36 f32 (sigma=9 odd -> conflict-free both sides)
    __syncthreads();
    const int bl = lane & 15;

    #pragma unroll
    for (int Hh = 0; Hh < 2; ++Hh) {
        #pragma unroll
        for (int bh = 0; bh < 2; ++bh) {
            if ((bl >> 3) == bh) {
                #pragma unroll
                for (int rr = 0; rr < 4; ++rr) {
                    #pragma unroll
                    for (int grp = 0; grp < 2; ++grp) {
                        int rp = (4 * hc + rr) * 8 + (bl & 7);
                        f32x4 v;
                        v[0] = acc[grp * 4 + 0][Hh][rr];
                        v[1] = acc[grp * 4 + 1][Hh][rr];
                        v[2] = acc[grp * 4 + 2][Hh][rr];
                        v[3] = acc[grp * 4 + 3][Hh][rr];
                        *reinterpret_cast<f32x4*>(scr + rp * 36 + wv * 8 + grp * 4) = v;
                    }
                }
            }
            __syncthreads();
            #pragma unroll
            for (int it = 0; it < 4; ++it) {
                int R = it * 32 + (tid >> 3);    // 0..127
                int C = tid & 7;
                int o15 = R >> 3, B = R & 7;
                f32x4 v = *reinterpret_cast<const f32x4*>(scr + R * 36 + C * 4);
                *reinterpret_cast<f32x4*>(
                    out + ((size_t)(bh * 8 + B) * CH + Hh * 16 + o15) * NN
                        + n0 + C * 4) = v;
            }
            __syncthreads();
        }
    }
}

extern "C" void kernel_launch(void* const* d_in, const int* in_sizes, int n_in,
                              void* d_out, int out_size, void* d_ws, size_t ws_size,
                              hipStream_t stream) {
    const float* x    = (const float*)d_in[0];
    const float* W    = (const float*)d_in[1];
    const float* bias = (const float*)d_in[2];
    float* out        = (float*)d_out;

    const int blocks = (NN + NT - 1) / NT;   // 1563
    localconv1d_kernel<<<blocks, TPB, 0, stream>>>(x, W, bias, out);
}

// Round 7
// 95.484 us; speedup vs baseline: 1.3426x; 1.0239x over previous
//
#include <hip/hip_runtime.h>

// out[b,o,n] = sum_h W[n,o,h] * x[b,h,n] + bias[n,o]
// x: [16][32][50000] f32, W: [50000][32][32] f32, bias: [50000][32] f32
// Per node: D[o 32][b 16] = W_n[32o x 32h] . X_n[32h x 16b] via 2x mfma 16x16x32 bf16.
// W streamed HBM->LDS (global_load_lds, frag-order-permuted source), per-wave
// double-buffered, counted vmcnt, no barriers in the main loop.
// R7: TPB=512 (8 waves), 68KB LDS -> 2 blocks/CU = 16 waves/CU.

#define NN 50000
#define CH 32
#define NT 32          // nodes per block
#define TPB 512        // 8 waves; wave wv owns nodes wv*4 .. wv*4+3
#define NXCD 8

typedef __attribute__((ext_vector_type(8))) short bf16x8;
typedef __attribute__((ext_vector_type(4))) float f32x4;
typedef __attribute__((ext_vector_type(4))) unsigned short bf16x4;
typedef float __attribute__((address_space(1))) gf32;
typedef float __attribute__((address_space(3))) lf32;

__device__ inline unsigned short f2bf(float f) {
    union { float f; unsigned u; } v; v.f = f;
    return (unsigned short)((v.u + 0x7fffu + ((v.u >> 16) & 1u)) >> 16);
}

__global__ __launch_bounds__(TPB, 4)
void localconv1d_kernel(const float* __restrict__ x,
                        const float* __restrict__ W,
                        const float* __restrict__ bias,
                        float* __restrict__ out) {
    // LDS carve: [0,32768) x-tile bf16 frags (reused as f32 scratch in epilogue)
    //            [32768,65536) W dbuf: wave wv at +wv*4096, buf at +(s&1)*2048
    //            [65536,69632) bias tile (1024 f32)
    __shared__ char smem[69632];
    unsigned short* xs   = (unsigned short*)smem;
    char*           wlds = smem + 32768;
    float*          blds = (float*)(smem + 65536);
    float*          scr  = (float*)smem;

    const int tid  = threadIdx.x;
    const int lane = tid & 63;
    const int wv   = tid >> 6;

    // ---- bijective XCD-aware block swizzle (nwg = 1563 = 8*195 + 3) ----
    const int nwg  = (NN + NT - 1) / NT;
    const int q    = nwg / NXCD;
    const int r    = nwg % NXCD;
    const int orig = blockIdx.x;
    const int xcd  = orig % NXCD;
    const int wgid = (xcd < r ? xcd * (q + 1) : r * (q + 1) + (xcd - r) * q)
                     + orig / NXCD;
    int n0 = wgid * NT;
    if (n0 > NN - NT) n0 = NN - NT;   // tail: overlap-recompute (identical dup writes)

    // ---- bias -> LDS (drained at staging barrier; waves 0..3 only) ----
    if (wv < 4)
        __builtin_amdgcn_global_load_lds(
            (const gf32*)(bias + (size_t)n0 * CH + wv * 256 + lane * 4),
            (lf32*)(blds + wv * 256), 16, 0, 0);

    // ---- stage x -> LDS bf16 B-fragments (R5/R6-validated layout) ----
    {
        const int chunk = tid & 7;
        float4 xv[2][4];
        #pragma unroll
        for (int u = 0; u < 2; ++u) {
            int gi = (tid >> 3) + u * 64;             // 0..127
            #pragma unroll
            for (int k = 0; k < 4; ++k) {
                int row = gi * 4 + k;                 // b*32 + h
                xv[u][k] = *reinterpret_cast<const float4*>(
                    x + (size_t)row * NN + n0 + chunk * 4);
            }
        }
        #pragma unroll
        for (int u = 0; u < 2; ++u) {
            int gi = (tid >> 3) + u * 64;
            int b  = gi >> 3;
            int h4 = gi & 7;
            int hg = h4 >> 1;
            int jb = (h4 & 1) * 8;
            #pragma unroll
            for (int c = 0; c < 4; ++c) {
                int nn = chunk * 4 + c;
                unsigned base = (unsigned)(nn * 1024 + hg * 256 + b * 16 + jb);
                base ^= ((unsigned)(nn >> 2) & 7u) << 4;
                bf16x4 pk;
                pk[0] = f2bf(((const float*)&xv[u][0])[c]);
                pk[1] = f2bf(((const float*)&xv[u][1])[c]);
                pk[2] = f2bf(((const float*)&xv[u][2])[c]);
                pk[3] = f2bf(((const float*)&xv[u][3])[c]);
                *reinterpret_cast<bf16x4*>((char*)xs + base) = pk;
            }
        }
    }
    __syncthreads();   // x + bias ready; vmcnt drained to 0 here

    // ---- W pipeline: step s = node(g=s>>1) x o-half(H=s&1), 2KB per step ----
    #define ISSUE_W(s_)                                                          \
        do {                                                                     \
            int g_ = (s_) >> 1, H_ = (s_) & 1;                                   \
            const float* src_ = W + (size_t)(n0 + wv * 4 + g_) * 1024            \
                                + (16 * H_ + (lane & 15)) * 32 + (lane >> 4) * 8;\
            char* dst_ = wlds + wv * 4096 + ((s_) & 1) * 2048;                   \
            __builtin_amdgcn_global_load_lds((const gf32*)src_,                  \
                                             (lf32*)dst_, 16, 0, 0);             \
            __builtin_amdgcn_global_load_lds((const gf32*)(src_ + 4),            \
                                             (lf32*)(dst_ + 1024), 16, 0, 0);    \
        } while (0)

    ISSUE_W(0);
    ISSUE_W(1);

    const int hc = lane >> 4;
    f32x4 acc[4][2];

    #pragma unroll
    for (int s = 0; s < 8; ++s) {
        if (s == 7) { asm volatile("s_waitcnt vmcnt(0)" ::: "memory"); }
        else        { asm volatile("s_waitcnt vmcnt(2)" ::: "memory"); }
        __builtin_amdgcn_sched_barrier(0);

        const int g  = s >> 1;
        const int Hh = s & 1;
        const int nn = wv * 4 + g;

        const char* wb = wlds + wv * 4096 + (s & 1) * 2048;
        f32x4 wlo = *reinterpret_cast<const f32x4*>(wb + lane * 16);
        f32x4 whi = *reinterpret_cast<const f32x4*>(wb + 1024 + lane * 16);

        f32x4 cfr = *reinterpret_cast<const f32x4*>(blds + nn * 32 + 16 * Hh + 4 * hc);

        unsigned raddr = (unsigned)(nn * 1024 + lane * 16);
        raddr ^= ((unsigned)(nn >> 2) & 7u) << 4;
        bf16x8 bfrag = *reinterpret_cast<const bf16x8*>((const char*)xs + raddr);

        bf16x8 afrag;
        afrag[0] = f2bf(wlo[0]); afrag[1] = f2bf(wlo[1]);
        afrag[2] = f2bf(wlo[2]); afrag[3] = f2bf(wlo[3]);
        afrag[4] = f2bf(whi[0]); afrag[5] = f2bf(whi[1]);
        afrag[6] = f2bf(whi[2]); afrag[7] = f2bf(whi[3]);

        __builtin_amdgcn_sched_barrier(0);
        if (s + 2 < 8) ISSUE_W(s + 2);

        acc[g][Hh] = __builtin_amdgcn_mfma_f32_16x16x32_bf16(afrag, bfrag, cfr, 0, 0, 0);
    }

    // ---- epilogue: LDS transpose; every store writes 8 full 128B lines ----
    // scratch: 128 rows x stride 36 f32 (odd sigma -> conflict-free both sides)
    __syncthreads();
    const int bl = lane & 15;

    #pragma unroll
    for (int Hh = 0; Hh < 2; ++Hh) {
        #pragma unroll
        for (int bh = 0; bh < 2; ++bh) {
            if ((bl >> 3) == bh) {
                #pragma unroll
                for (int rr = 0; rr < 4; ++rr) {
                    int rp = (4 * hc + rr) * 8 + (bl & 7);
                    f32x4 v;
                    v[0] = acc[0][Hh][rr];
                    v[1] = acc[1][Hh][rr];
                    v[2] = acc[2][Hh][rr];
                    v[3] = acc[3][Hh][rr];
                    *reinterpret_cast<f32x4*>(scr + rp * 36 + wv * 4) = v;
                }
            }
            __syncthreads();
            #pragma unroll
            for (int it = 0; it < 2; ++it) {
                int R = it * 64 + (tid >> 3);    // 0..127
                int C = tid & 7;
                int o15 = R >> 3, B = R & 7;
                f32x4 v = *reinterpret_cast<const f32x4*>(scr + R * 36 + C * 4);
                *reinterpret_cast<f32x4*>(
                    out + ((size_t)(bh * 8 + B) * CH + Hh * 16 + o15) * NN
                        + n0 + C * 4) = v;
            }
            __syncthreads();
        }
    }
}

extern "C" void kernel_launch(void* const* d_in, const int* in_sizes, int n_in,
                              void* d_out, int out_size, void* d_ws, size_t ws_size,
                              hipStream_t stream) {
    const float* x    = (const float*)d_in[0];
    const float* W    = (const float*)d_in[1];
    const float* bias = (const float*)d_in[2];
    float* out        = (float*)d_out;

    const int blocks = (NN + NT - 1) / NT;   // 1563
    localconv1d_kernel<<<blocks, TPB, 0, stream>>>(x, W, bias, out);
}

// Round 8
// 93.099 us; speedup vs baseline: 1.3770x; 1.0256x over previous
//
#include <hip/hip_runtime.h>

// out[b,o,n] = sum_h W[n,o,h] * x[b,h,n] + bias[n,o]
// x: [16][32][50000] f32, W: [50000][32][32] f32, bias: [50000][32] f32
// Per node: D[o 32][b 16] = W_n[32o x 32h] . X_n[32h x 16b] via 2x mfma 16x16x32 bf16.
// R8: W streamed HBM->LDS with WAVE-CONTIGUOUS global_load_lds (full sector
// coalescing; the o-major frag shuffle moved to a swizzled LDS read).

#define NN 50000
#define CH 32
#define NT 32          // nodes per block
#define TPB 512        // 8 waves; wave wv owns nodes wv*4 .. wv*4+3
#define NXCD 8

typedef __attribute__((ext_vector_type(8))) short bf16x8;
typedef __attribute__((ext_vector_type(4))) float f32x4;
typedef __attribute__((ext_vector_type(4))) unsigned short bf16x4;
typedef float __attribute__((address_space(1))) gf32;
typedef float __attribute__((address_space(3))) lf32;

__device__ inline unsigned short f2bf(float f) {
    union { float f; unsigned u; } v; v.f = f;
    return (unsigned short)((v.u + 0x7fffu + ((v.u >> 16) & 1u)) >> 16);
}

__global__ __launch_bounds__(TPB, 4)
void localconv1d_kernel(const float* __restrict__ x,
                        const float* __restrict__ W,
                        const float* __restrict__ bias,
                        float* __restrict__ out) {
    // LDS carve: [0,32768) x-tile bf16 frags (reused as f32 scratch in epilogue)
    //            [32768,65536) W dbuf: wave wv at +wv*4096, buf at +(s&1)*2048
    //            [65536,69632) bias tile (1024 f32)
    __shared__ char smem[69632];
    unsigned short* xs   = (unsigned short*)smem;
    char*           wlds = smem + 32768;
    float*          blds = (float*)(smem + 65536);
    float*          scr  = (float*)smem;

    const int tid  = threadIdx.x;
    const int lane = tid & 63;
    const int wv   = tid >> 6;
    const int bl   = lane & 15;
    const int hc   = lane >> 4;

    // ---- bijective XCD-aware block swizzle (nwg = 1563 = 8*195 + 3) ----
    const int nwg  = (NN + NT - 1) / NT;
    const int q    = nwg / NXCD;
    const int r    = nwg % NXCD;
    const int orig = blockIdx.x;
    const int xcd  = orig % NXCD;
    const int wgid = (xcd < r ? xcd * (q + 1) : r * (q + 1) + (xcd - r) * q)
                     + orig / NXCD;
    int n0 = wgid * NT;
    if (n0 > NN - NT) n0 = NN - NT;   // tail: overlap-recompute (identical dup writes)

    // ---- bias -> LDS (drained at staging barrier; waves 0..3 only) ----
    if (wv < 4)
        __builtin_amdgcn_global_load_lds(
            (const gf32*)(bias + (size_t)n0 * CH + wv * 256 + lane * 4),
            (lf32*)(blds + wv * 256), 16, 0, 0);

    // ---- stage x -> LDS bf16 B-fragments (R5/R6/R7-validated layout) ----
    {
        const int chunk = tid & 7;
        float4 xv[2][4];
        #pragma unroll
        for (int u = 0; u < 2; ++u) {
            int gi = (tid >> 3) + u * 64;             // 0..127
            #pragma unroll
            for (int k = 0; k < 4; ++k) {
                int row = gi * 4 + k;                 // b*32 + h
                xv[u][k] = *reinterpret_cast<const float4*>(
                    x + (size_t)row * NN + n0 + chunk * 4);
            }
        }
        #pragma unroll
        for (int u = 0; u < 2; ++u) {
            int gi = (tid >> 3) + u * 64;
            int b  = gi >> 3;
            int h4 = gi & 7;
            int hg = h4 >> 1;
            int jb = (h4 & 1) * 8;
            #pragma unroll
            for (int c = 0; c < 4; ++c) {
                int nn = chunk * 4 + c;
                unsigned base = (unsigned)(nn * 1024 + hg * 256 + b * 16 + jb);
                base ^= ((unsigned)(nn >> 2) & 7u) << 4;
                bf16x4 pk;
                pk[0] = f2bf(((const float*)&xv[u][0])[c]);
                pk[1] = f2bf(((const float*)&xv[u][1])[c]);
                pk[2] = f2bf(((const float*)&xv[u][2])[c]);
                pk[3] = f2bf(((const float*)&xv[u][3])[c]);
                *reinterpret_cast<bf16x4*>((char*)xs + base) = pk;
            }
        }
    }
    __syncthreads();   // x + bias ready; vmcnt drained to 0 here

    // ---- W pipeline: step s = node(g=s>>1) x o-half(H=s&1), 2KB per step ----
    // Source is CONTIGUOUS per instruction (1KB span), with a within-128B XOR
    // permutation sigma(c)=c^((c>>3)&7) on the per-lane address so the LDS
    // holds chunks in swizzle order; frag read below undoes it (involution).
    const int lpermf = (lane * 4) ^ (((lane >> 3) & 7) << 2);  // float offset
    #define ISSUE_W(s_)                                                          \
        do {                                                                     \
            int g_ = (s_) >> 1, H_ = (s_) & 1;                                   \
            const float* base_ = W + (size_t)(n0 + wv * 4 + g_) * 1024           \
                                 + H_ * 512;                                     \
            char* dst_ = wlds + wv * 4096 + ((s_) & 1) * 2048;                   \
            __builtin_amdgcn_global_load_lds((const gf32*)(base_ + lpermf),      \
                                             (lf32*)dst_, 16, 0, 0);             \
            __builtin_amdgcn_global_load_lds((const gf32*)(base_ + 256 + lpermf),\
                                             (lf32*)(dst_ + 1024), 16, 0, 0);    \
        } while (0)

    ISSUE_W(0);
    ISSUE_W(1);

    f32x4 acc[4][2];

    #pragma unroll
    for (int s = 0; s < 8; ++s) {
        if (s == 7) { asm volatile("s_waitcnt vmcnt(0)" ::: "memory"); }
        else        { asm volatile("s_waitcnt vmcnt(2)" ::: "memory"); }
        __builtin_amdgcn_sched_barrier(0);

        const int g  = s >> 1;
        const int Hh = s & 1;
        const int nn = wv * 4 + g;

        // A fragment: chunks f0 = bl*8 + hc*2, f1 = f0+1; slot = f ^ (bl&7)
        const char* wb = wlds + wv * 4096 + (s & 1) * 2048;
        const int slot0 = (bl * 8 + hc * 2) ^ (bl & 7);
        f32x4 wlo = *reinterpret_cast<const f32x4*>(wb + slot0 * 16);
        f32x4 whi = *reinterpret_cast<const f32x4*>(wb + (slot0 ^ 1) * 16);

        f32x4 cfr = *reinterpret_cast<const f32x4*>(blds + nn * 32 + 16 * Hh + 4 * hc);

        unsigned raddr = (unsigned)(nn * 1024 + lane * 16);
        raddr ^= ((unsigned)(nn >> 2) & 7u) << 4;
        bf16x8 bfrag = *reinterpret_cast<const bf16x8*>((const char*)xs + raddr);

        bf16x8 afrag;
        afrag[0] = f2bf(wlo[0]); afrag[1] = f2bf(wlo[1]);
        afrag[2] = f2bf(wlo[2]); afrag[3] = f2bf(wlo[3]);
        afrag[4] = f2bf(whi[0]); afrag[5] = f2bf(whi[1]);
        afrag[6] = f2bf(whi[2]); afrag[7] = f2bf(whi[3]);

        __builtin_amdgcn_sched_barrier(0);
        if (s + 2 < 8) ISSUE_W(s + 2);

        acc[g][Hh] = __builtin_amdgcn_mfma_f32_16x16x32_bf16(afrag, bfrag, cfr, 0, 0, 0);
    }

    // ---- epilogue: LDS transpose; every store writes full 128B lines ----
    __syncthreads();

    #pragma unroll
    for (int Hh = 0; Hh < 2; ++Hh) {
        #pragma unroll
        for (int bh = 0; bh < 2; ++bh) {
            if ((bl >> 3) == bh) {
                #pragma unroll
                for (int rr = 0; rr < 4; ++rr) {
                    int rp = (4 * hc + rr) * 8 + (bl & 7);
                    f32x4 v;
                    v[0] = acc[0][Hh][rr];
                    v[1] = acc[1][Hh][rr];
                    v[2] = acc[2][Hh][rr];
                    v[3] = acc[3][Hh][rr];
                    *reinterpret_cast<f32x4*>(scr + rp * 36 + wv * 4) = v;
                }
            }
            __syncthreads();
            #pragma unroll
            for (int it = 0; it < 2; ++it) {
                int R = it * 64 + (tid >> 3);    // 0..127
                int C = tid & 7;
                int o15 = R >> 3, B = R & 7;
                f32x4 v = *reinterpret_cast<const f32x4*>(scr + R * 36 + C * 4);
                *reinterpret_cast<f32x4*>(
                    out + ((size_t)(bh * 8 + B) * CH + Hh * 16 + o15) * NN
                        + n0 + C * 4) = v;
            }
            __syncthreads();
        }
    }
}

extern "C" void kernel_launch(void* const* d_in, const int* in_sizes, int n_in,
                              void* d_out, int out_size, void* d_ws, size_t ws_size,
                              hipStream_t stream) {
    const float* x    = (const float*)d_in[0];
    const float* W    = (const float*)d_in[1];
    const float* bias = (const float*)d_in[2];
    float* out        = (float*)d_out;

    const int blocks = (NN + NT - 1) / NT;   // 1563
    localconv1d_kernel<<<blocks, TPB, 0, stream>>>(x, W, bias, out);
}